// Round 3
// baseline (161.639 us; speedup 1.0000x reference)
//
#include <hip/hip_runtime.h>
#include <math.h>

#ifndef M_PI
#define M_PI 3.14159265358979323846
#endif

#define DMODEL 256
#define NSTATE 64
#define LSEQ   8192
#define INVL   (1.0f/8192.0f)

// Workspace layout (bytes). tw 48 KB + dn5 1.25 MB + cdt 1 KB.
#define OFF_TW  0                                  // float2[6144]: e^{+2pi i j/L}, j<3L/4
#define OFF_DN  (6144*8)                           // float4[5*DMODEL*NSTATE] duplicated pairs
#define OFF_CDT (OFF_DN + DMODEL*NSTATE*80)        // float[DMODEL]: 2/dt

__device__ __forceinline__ float sin_rev(float r) {
#if __has_builtin(__builtin_amdgcn_sinf)
  return __builtin_amdgcn_sinf(r);        // D = sin(S0 * 2pi), input in revolutions
#else
  return __sinf(r * 6.283185307179586f);
#endif
}
__device__ __forceinline__ float cos_rev(float r) {
#if __has_builtin(__builtin_amdgcn_cosf)
  return __builtin_amdgcn_cosf(r);
#else
  return __cosf(r * 6.283185307179586f);
#endif
}

__device__ __forceinline__ float2 cmul(float2 a, float2 b) {
  return make_float2(a.x*b.x - a.y*b.y, a.x*b.y + a.y*b.x);
}

// Packed fp32 (CDNA full-rate): 2 FLOPs per lane per issue slot.
__device__ __forceinline__ float2 pk_add(float2 a, float2 b) {
  float2 d; asm("v_pk_add_f32 %0, %1, %2" : "=v"(d) : "v"(a), "v"(b)); return d;
}
__device__ __forceinline__ float2 pk_mul(float2 a, float2 b) {
  float2 d; asm("v_pk_mul_f32 %0, %1, %2" : "=v"(d) : "v"(a), "v"(b)); return d;
}
__device__ __forceinline__ float2 pk_fma(float2 a, float2 b, float2 c) {
  float2 d; asm("v_pk_fma_f32 %0, %1, %2, %3" : "=v"(d) : "v"(a), "v"(b), "v"(c)); return d;
}

// K_hat/L from the 4 complex sums. PRB*BRP = (S1+iS2)(S1-iS2) = S1^2 + S2^2.
// Prefactor 2/(1+z) = 1 + i*T; fold 1/L here.
__device__ __forceinline__ float2 woodbury(float2 S1, float2 S2, float2 S3,
                                           float2 S4, float T) {
  float nr = (S1.x*S1.x - S1.y*S1.y) + (S2.x*S2.x - S2.y*S2.y);
  float ni = 2.0f*(S1.x*S1.y + S2.x*S2.y);
  float dr = 1.0f + S3.x, di = S3.y;
  float inv = __builtin_amdgcn_rcpf(fmaf(dr, dr, di*di));
  float qr = (nr*dr + ni*di) * inv;
  float qi = (ni*dr - nr*di) * inv;
  float vr = S4.x - qr, vi = S4.y - qi;
  return make_float2((vr - T*vi)*INVL, (vi + T*vr)*INVL);
}

// ---------------------------------------------------------------- precompute
// dn5 layout per (d,n), 5 x float4 of DUPLICATED pairs (for packed VOP3P ops):
//   e0 = (-lim, -lim, sp^2, sp^2)
//   e1 = (w1r*sp, w1r*sp, w1i*sp, w1i*sp)     w1 = conj(P)*B
//   e2 = (w2*sp,  w2*sp,  w3*sp,  w3*sp)      w2 = |P|^2, w3 = |B|^2
//   e3 = (-w1r, -w1r, -w1i, -w1i)
//   e4 = (-w2,  -w2,  -w3,  -w3)
// Re-sums use (w*sp)*inv; Im-sums use (-w)*(dim*inv).
__global__ __launch_bounds__(256) void precompute_kernel(
    const float* __restrict__ Lre, const float* __restrict__ Lim,
    const float* __restrict__ Pre, const float* __restrict__ Pim,
    const float* __restrict__ Bre, const float* __restrict__ Bim,
    const float* __restrict__ log_dt, char* __restrict__ ws)
{
  const int t = blockIdx.x * blockDim.x + threadIdx.x;  // 0..16383
  float2* tw  = (float2*)(ws + OFF_TW);
  float4* dn  = (float4*)(ws + OFF_DN);
  float*  cdt = (float*)(ws + OFF_CDT);

  if (t < 6144) {
    double th = (2.0 * M_PI / (double)LSEQ) * (double)t;
    double s, c; sincos(th, &s, &c);
    tw[t] = make_float2((float)c, (float)s);
  }
  {
    float lre = Lre[t], lim = Lim[t];
    float pre = Pre[t], pim = Pim[t];
    float bre = Bre[t], bim = Bim[t];
    float sp = fmaxf(lre, 0.0f) + log1pf(expf(-fabsf(lre)));  // softplus
    float w1r = pre*bre + pim*bim;   // Re conj(P)*B
    float w1i = pre*bim - pim*bre;   // Im conj(P)*B
    float w2  = pre*pre + pim*pim;   // |P|^2
    float w3  = bre*bre + bim*bim;   // |B|^2
    dn[5*t]   = make_float4(-lim, -lim, sp*sp, sp*sp);
    dn[5*t+1] = make_float4(w1r*sp, w1r*sp, w1i*sp, w1i*sp);
    dn[5*t+2] = make_float4(w2*sp, w2*sp, w3*sp, w3*sp);
    dn[5*t+3] = make_float4(-w1r, -w1r, -w1i, -w1i);
    dn[5*t+4] = make_float4(-w2, -w2, -w3, -w3);
  }
  if (t < DMODEL) cdt[t] = 2.0f * expf(-log_dt[t]);
}

// ---------------------------------------------------------------- fused cauchy + ifft
// One block per d (grid == 256 CUs -> exactly 1 block/CU; launch_bounds(1024,4)
// caps at 128 VGPR which is the true per-wave budget at 4 waves/SIMD).
// Phase 1: packed-f32 Cauchy. The A-half (k<4096) and B-half (k+4096) of each
// pair run in the lo/hi slots of v_pk_* ops: 11 packed VALU + 2 rcp per (n,pair)
// instead of 22 VALU + 2 rcp. Two pairs per outer pass amortize the 5 table
// loads; table pointer is laundered through asm so loads are vector loads
// straight into VGPR pairs (no SGPR->VGPR movs feeding the packed asm).
// Phase 2: 6 radix-4 DIT stages in LDS. Output natural order.
__global__ __launch_bounds__(1024, 4) void fused_kernel(
    const float4* __restrict__ dn_all, const float* __restrict__ cdt,
    const float2* __restrict__ tw, const float* __restrict__ Din,
    float* __restrict__ out)
{
  __shared__ __align__(16) float2 xy[LSEQ];   // 64 KB
  const int d = blockIdx.x;
  const int t = threadIdx.x;                  // 0..1023
  const float c = cdt[d];                     // 2/dt, wave-uniform

  // Launder the table pointer: compiler treats it as divergent -> global_load
  // into VGPRs (uniform address = 1 broadcast transaction, L1-resident 5KB).
  const float4* dnv = dn_all + (size_t)d * (5*NSTATE);
  asm("" : "+v"(dnv));

  // ---- Phase 1: two outer passes, two (kA, kA+4096) pairs each.
  for (int pass = 0; pass < 2; ++pass) {
    float TA[2], TB[2];
    float2 gAB[2];
    float2 S[2][8];   // [pair][S1x,S2x,S3x,S4x,S1y,S2y,S3y,S4y]; x=Re-sum, y=Im-sum; packed (A,B)
#pragma unroll
    for (int j = 0; j < 2; ++j) {
      const int b = t + ((2*pass + j) << 10); // pair id 0..4095
      const unsigned p = (unsigned)(2*b);
      const unsigned r = __brev(p) >> 19;     // 13-bit reversal
      const int kA = (int)((r & 0x1000u) | ((r & 0x0555u) << 1) | ((r & 0x0AAAu) >> 1));
      // kA < 4096. T = tan(pi k / L); (1-z)/(1+z) = i*T exactly.
      const float rev = (float)kA * (1.0f/16384.0f);
      const float sA = sin_rev(rev), cA = cos_rev(rev);
      float ta = sA * __builtin_amdgcn_rcpf(cA);
      float tb = -cA * __builtin_amdgcn_rcpf(sA);   // tan(x + pi/2) = -cot(x)
      ta = fminf(fmaxf(ta, -1e7f), 1e7f);
      tb = fminf(fmaxf(tb, -1e7f), 1e7f);
      TA[j] = ta; TB[j] = tb;
      gAB[j] = make_float2(c * ta, c * tb);   // g = i*gIm, purely imaginary
#pragma unroll
      for (int q = 0; q < 8; ++q) S[j][q] = make_float2(0.0f, 0.0f);
    }

#pragma unroll 2
    for (int n = 0; n < NSTATE; ++n) {
      const float4 e0 = dnv[5*n];
      const float4 e1 = dnv[5*n+1];
      const float4 e2 = dnv[5*n+2];
      const float4 e3 = dnv[5*n+3];
      const float4 e4 = dnv[5*n+4];
      const float2 nl2  = make_float2(e0.x, e0.y);   // (-lim, -lim)
      const float2 s2_2 = make_float2(e0.z, e0.w);   // (sp^2, sp^2)
      const float2 w1rs = make_float2(e1.x, e1.y);
      const float2 w1is = make_float2(e1.z, e1.w);
      const float2 w2s  = make_float2(e2.x, e2.y);
      const float2 w3s  = make_float2(e2.z, e2.w);
      const float2 nw1r = make_float2(e3.x, e3.y);
      const float2 nw1i = make_float2(e3.z, e3.w);
      const float2 nw2  = make_float2(e4.x, e4.y);
      const float2 nw3  = make_float2(e4.z, e4.w);
#pragma unroll
      for (int j = 0; j < 2; ++j) {
        const float2 dimAB = pk_add(gAB[j], nl2);            // g - lim (both halves)
        const float2 denAB = pk_fma(dimAB, dimAB, s2_2);     // dim^2 + sp^2
        float2 invAB;
        invAB.x = __builtin_amdgcn_rcpf(denAB.x);
        invAB.y = __builtin_amdgcn_rcpf(denAB.y);
        const float2 vAB = pk_mul(dimAB, invAB);             // Im R = -v; Re R = sp*inv
        S[j][0] = pk_fma(w1rs, invAB, S[j][0]);
        S[j][1] = pk_fma(w1is, invAB, S[j][1]);
        S[j][2] = pk_fma(w2s,  invAB, S[j][2]);
        S[j][3] = pk_fma(w3s,  invAB, S[j][3]);
        S[j][4] = pk_fma(nw1r, vAB, S[j][4]);
        S[j][5] = pk_fma(nw1i, vAB, S[j][5]);
        S[j][6] = pk_fma(nw2,  vAB, S[j][6]);
        S[j][7] = pk_fma(nw3,  vAB, S[j][7]);
      }
    }

    // Tail: unpack halves, Woodbury, radix-2 fold, 16B conflict-free LDS store.
#pragma unroll
    for (int j = 0; j < 2; ++j) {
      const float2 S1A = make_float2(S[j][0].x, S[j][4].x);
      const float2 S2A = make_float2(S[j][1].x, S[j][5].x);
      const float2 S3A = make_float2(S[j][2].x, S[j][6].x);
      const float2 S4A = make_float2(S[j][3].x, S[j][7].x);
      const float2 S1B = make_float2(S[j][0].y, S[j][4].y);
      const float2 S2B = make_float2(S[j][1].y, S[j][5].y);
      const float2 S3B = make_float2(S[j][2].y, S[j][6].y);
      const float2 S4B = make_float2(S[j][3].y, S[j][7].y);
      const float2 KA = woodbury(S1A, S2A, S3A, S4A, TA[j]);
      const float2 KB = woodbury(S1B, S2B, S3B, S4B, TB[j]);
      ((float4*)xy)[t + ((2*pass + j) << 10)] =
          make_float4(KA.x + KB.x, KA.y + KB.y, KA.x - KB.x, KA.y - KB.y);
    }
  }
  __syncthreads();

  // ---- Phase 2: six radix-4 DIT stages, spans h = 2,8,32,128,512,2048.
#pragma unroll
  for (int s = 0; s < 6; ++s) {
    const int h = 2 << (2*s);
    const int twsh = 10 - 2*s;                // tw stride = L/(4h) = 1024>>2s
#pragma unroll
    for (int j = 0; j < 2; ++j) {
      const int bb = t + (j << 10);           // butterfly id 0..2047
      const int pos = bb & (h - 1);
      const int i0 = ((bb >> (1 + 2*s)) << (3 + 2*s)) + pos;
      const int ti = pos << twsh;
      const float2 w1 = tw[ti];
      const float2 w2 = tw[2*ti];
      const float2 w3 = tw[3*ti];
      const float2 x0 = xy[i0];
      const float2 x1 = xy[i0 + h];
      const float2 x2 = xy[i0 + 2*h];
      const float2 x3 = xy[i0 + 3*h];
      const float2 t1 = cmul(w1, x1);
      const float2 t2 = cmul(w2, x2);
      const float2 t3 = cmul(w3, x3);
      const float2 u0 = make_float2(x0.x + t2.x, x0.y + t2.y);
      const float2 u1 = make_float2(x0.x - t2.x, x0.y - t2.y);
      const float2 u2 = make_float2(t1.x + t3.x, t1.y + t3.y);
      const float2 vv = make_float2(t1.x - t3.x, t1.y - t3.y);
      xy[i0]         = make_float2(u0.x + u2.x, u0.y + u2.y);   // Y0
      xy[i0 + h]     = make_float2(u1.x - vv.y, u1.y + vv.x);   // Y1 = u1 + i*vv
      xy[i0 + 2*h]   = make_float2(u0.x - u2.x, u0.y - u2.y);   // Y2
      xy[i0 + 3*h]   = make_float2(u1.x + vv.y, u1.y - vv.x);   // Y3 = u1 - i*vv
    }
    __syncthreads();
  }

  // ---- Store real part (already scaled by 1/L), natural order, coalesced.
  float* orow = out + (size_t)d * LSEQ;
#pragma unroll
  for (int j = 0; j < 8; ++j) orow[t + (j << 10)] = xy[t + (j << 10)].x;

  // second tuple output: D passthrough (zeros buffer)
  if (d == 0 && t < DMODEL) out[(size_t)DMODEL * LSEQ + t] = Din[t];
}

// ---------------------------------------------------------------- launch
extern "C" void kernel_launch(void* const* d_in, const int* in_sizes, int n_in,
                              void* d_out, int out_size, void* d_ws, size_t ws_size,
                              hipStream_t stream)
{
  const float* Lre    = (const float*)d_in[0];
  const float* Lim    = (const float*)d_in[1];
  const float* Pre    = (const float*)d_in[2];
  const float* Pim    = (const float*)d_in[3];
  const float* Bre    = (const float*)d_in[4];
  const float* Bim    = (const float*)d_in[5];
  const float* log_dt = (const float*)d_in[6];
  const float* Din    = (const float*)d_in[7];
  float* out = (float*)d_out;
  char* ws = (char*)d_ws;

  hipLaunchKernelGGL(precompute_kernel, dim3(64), dim3(256), 0, stream,
                     Lre, Lim, Pre, Pim, Bre, Bim, log_dt, ws);
  hipLaunchKernelGGL(fused_kernel, dim3(DMODEL), dim3(1024), 0, stream,
                     (const float4*)(ws + OFF_DN), (const float*)(ws + OFF_CDT),
                     (const float2*)(ws + OFF_TW), Din, out);
}

// Round 4
// 133.569 us; speedup vs baseline: 1.2102x; 1.2102x over previous
//
#include <hip/hip_runtime.h>
#include <math.h>

#ifndef M_PI
#define M_PI 3.14159265358979323846
#endif

#define DMODEL 256
#define NSTATE 64
#define LSEQ   8192
#define INVL   (1.0f/8192.0f)

// Workspace layout (bytes). tw 48 KB + dn5 1.25 MB + cdt 1 KB.
#define OFF_TW  0                                  // float2[6144]: e^{+2pi i j/L}, j<3L/4
#define OFF_DN  (6144*8)                           // float2[10*DMODEL*NSTATE] duplicated pairs
#define OFF_CDT (OFF_DN + DMODEL*NSTATE*80)        // float[DMODEL]: 2/dt

__device__ __forceinline__ float sin_rev(float r) {
#if __has_builtin(__builtin_amdgcn_sinf)
  return __builtin_amdgcn_sinf(r);        // D = sin(S0 * 2pi), input in revolutions
#else
  return __sinf(r * 6.283185307179586f);
#endif
}
__device__ __forceinline__ float cos_rev(float r) {
#if __has_builtin(__builtin_amdgcn_cosf)
  return __builtin_amdgcn_cosf(r);
#else
  return __cosf(r * 6.283185307179586f);
#endif
}

__device__ __forceinline__ float2 cmul(float2 a, float2 b) {
  return make_float2(a.x*b.x - a.y*b.y, a.x*b.y + a.y*b.x);
}

// Packed fp32 (CDNA full-rate VOP3P, 64-bit register pairs): 2 FLOPs/lane/issue.
// Weight operands live in SGPR pairs (wave-uniform, duplicated lo==hi);
// each instruction reads exactly ONE scalar operand (legal: <=1 SGPR/VALU op).
__device__ __forceinline__ float2 pk_add_sv(float2 s, float2 v) {
  float2 d; asm("v_pk_add_f32 %0, %1, %2" : "=v"(d) : "s"(s), "v"(v)); return d;
}
__device__ __forceinline__ float2 pk_mul_vv(float2 a, float2 b) {
  float2 d; asm("v_pk_mul_f32 %0, %1, %2" : "=v"(d) : "v"(a), "v"(b)); return d;
}
__device__ __forceinline__ float2 pk_fma_vvs(float2 a, float2 b, float2 s) {
  float2 d; asm("v_pk_fma_f32 %0, %1, %2, %3" : "=v"(d) : "v"(a), "v"(b), "s"(s)); return d;
}
__device__ __forceinline__ float2 pk_fma_svv(float2 s, float2 b, float2 c) {
  float2 d; asm("v_pk_fma_f32 %0, %1, %2, %3" : "=v"(d) : "s"(s), "v"(b), "v"(c)); return d;
}

// K_hat/L from the 4 complex sums. PRB*BRP = (S1+iS2)(S1-iS2) = S1^2 + S2^2.
// Prefactor 2/(1+z) = 1 + i*T; fold 1/L here.
__device__ __forceinline__ float2 woodbury(float2 S1, float2 S2, float2 S3,
                                           float2 S4, float T) {
  float nr = (S1.x*S1.x - S1.y*S1.y) + (S2.x*S2.x - S2.y*S2.y);
  float ni = 2.0f*(S1.x*S1.y + S2.x*S2.y);
  float dr = 1.0f + S3.x, di = S3.y;
  float inv = __builtin_amdgcn_rcpf(fmaf(dr, dr, di*di));
  float qr = (nr*dr + ni*di) * inv;
  float qi = (ni*dr - nr*di) * inv;
  float vr = S4.x - qr, vi = S4.y - qi;
  return make_float2((vr - T*vi)*INVL, (vi + T*vr)*INVL);
}

// ---------------------------------------------------------------- precompute
// dn layout per (d,n), 10 float2 of DUPLICATED pairs (for packed VOP3P ops):
//   [0]=(-lim,-lim) [1]=(sp^2,sp^2) [2]=(w1r*sp,..) [3]=(w1i*sp,..) [4]=(w2*sp,..)
//   [5]=(w3*sp,..)  [6]=(-w1r,..)   [7]=(-w1i,..)   [8]=(-w2,..)    [9]=(-w3,..)
// Re-sums use (w*sp)*inv; Im-sums use (-w)*(dim*inv).
__global__ __launch_bounds__(256) void precompute_kernel(
    const float* __restrict__ Lre, const float* __restrict__ Lim,
    const float* __restrict__ Pre, const float* __restrict__ Pim,
    const float* __restrict__ Bre, const float* __restrict__ Bim,
    const float* __restrict__ log_dt, char* __restrict__ ws)
{
  const int t = blockIdx.x * blockDim.x + threadIdx.x;  // 0..16383
  float2* tw  = (float2*)(ws + OFF_TW);
  float2* dn  = (float2*)(ws + OFF_DN);
  float*  cdt = (float*)(ws + OFF_CDT);

  if (t < 6144) {
    double th = (2.0 * M_PI / (double)LSEQ) * (double)t;
    double s, c; sincos(th, &s, &c);
    tw[t] = make_float2((float)c, (float)s);
  }
  {
    float lre = Lre[t], lim = Lim[t];
    float pre = Pre[t], pim = Pim[t];
    float bre = Bre[t], bim = Bim[t];
    float sp = fmaxf(lre, 0.0f) + log1pf(expf(-fabsf(lre)));  // softplus
    float w1r = pre*bre + pim*bim;   // Re conj(P)*B
    float w1i = pre*bim - pim*bre;   // Im conj(P)*B
    float w2  = pre*pre + pim*pim;   // |P|^2
    float w3  = bre*bre + bim*bim;   // |B|^2
    float2* e = dn + 10*(size_t)t;
    e[0] = make_float2(-lim, -lim);
    e[1] = make_float2(sp*sp, sp*sp);
    e[2] = make_float2(w1r*sp, w1r*sp);
    e[3] = make_float2(w1i*sp, w1i*sp);
    e[4] = make_float2(w2*sp, w2*sp);
    e[5] = make_float2(w3*sp, w3*sp);
    e[6] = make_float2(-w1r, -w1r);
    e[7] = make_float2(-w1i, -w1i);
    e[8] = make_float2(-w2, -w2);
    e[9] = make_float2(-w3, -w3);
  }
  if (t < DMODEL) cdt[t] = 2.0f * expf(-log_dt[t]);
}

// ---------------------------------------------------------------- fused cauchy + ifft
// One block per d; launch_bounds(1024,4) -> 128-VGPR budget (4 waves/SIMD).
// Phase 1: packed-f32 Cauchy, SINGLE walk of the n-table with all four
// (kA, kA+4096) pairs live. A-half/B-half of each pair occupy lo/hi slots of
// v_pk_* ops (11 packed VALU + 2 rcp per (n,pair) vs 22+2 unpacked). Weights
// stream through SGPRs (s_load, wave-uniform) directly into the VOP3P scalar
// operand slot -- no per-lane addresses, no v_mov staging.
// Phase 2: 6 radix-4 DIT stages in LDS. Output natural order.
__global__ __launch_bounds__(1024, 4) void fused_kernel(
    const float2* __restrict__ dn_all, const float* __restrict__ cdt,
    const float2* __restrict__ tw, const float* __restrict__ Din,
    float* __restrict__ out)
{
  __shared__ __align__(16) float2 xy[LSEQ];   // 64 KB
  const int d = blockIdx.x;
  const int t = threadIdx.x;                  // 0..1023
  const float c = cdt[d];                     // 2/dt, wave-uniform
  const float2* dn = dn_all + (size_t)d * (10*NSTATE);

  // ---- Phase 1 setup: 4 pairs per thread.
  float TA[4], TB[4];
  float2 gAB[4];
  float2 S[4][8];   // [pair][S1x,S2x,S3x,S4x,S1y,S2y,S3y,S4y]; x=Re-sum, y=Im-sum; packed (A,B)
#pragma unroll
  for (int j = 0; j < 4; ++j) {
    const int b = t + (j << 10);              // pair id 0..4095
    const unsigned p = (unsigned)(2*b);
    const unsigned r = __brev(p) >> 19;       // 13-bit reversal
    const int kA = (int)((r & 0x1000u) | ((r & 0x0555u) << 1) | ((r & 0x0AAAu) >> 1));
    // kA < 4096. T = tan(pi k / L); (1-z)/(1+z) = i*T exactly (no cancellation).
    const float rev = (float)kA * (1.0f/16384.0f);
    const float sA = sin_rev(rev), cA = cos_rev(rev);
    float ta = sA * __builtin_amdgcn_rcpf(cA);
    float tb = -cA * __builtin_amdgcn_rcpf(sA);   // tan(x + pi/2) = -cot(x)
    ta = fminf(fmaxf(ta, -1e7f), 1e7f);
    tb = fminf(fmaxf(tb, -1e7f), 1e7f);
    TA[j] = ta; TB[j] = tb;
    gAB[j] = make_float2(c * ta, c * tb);     // g = i*gIm, purely imaginary
#pragma unroll
    for (int q = 0; q < 8; ++q) S[j][q] = make_float2(0.0f, 0.0f);
  }

  // ---- Phase 1 main loop: ONE walk of the 64-entry table for all 8 points.
#pragma unroll 2
  for (int n = 0; n < NSTATE; ++n) {
    const float2* e = dn + 10*n;
    const float2 nl2  = e[0];   // (-lim,-lim)      wave-uniform -> SGPR pair
    const float2 s2_2 = e[1];   // (sp^2,sp^2)
    const float2 w1rs = e[2];
    const float2 w1is = e[3];
    const float2 w2s  = e[4];
    const float2 w3s  = e[5];
    const float2 nw1r = e[6];
    const float2 nw1i = e[7];
    const float2 nw2  = e[8];
    const float2 nw3  = e[9];
#pragma unroll
    for (int j = 0; j < 4; ++j) {
      const float2 dimAB = pk_add_sv(nl2, gAB[j]);           // g - lim (both halves)
      const float2 denAB = pk_fma_vvs(dimAB, dimAB, s2_2);   // dim^2 + sp^2
      float2 invAB;
      invAB.x = __builtin_amdgcn_rcpf(denAB.x);
      invAB.y = __builtin_amdgcn_rcpf(denAB.y);
      const float2 vAB = pk_mul_vv(dimAB, invAB);            // Im R = -v; Re R = sp*inv
      S[j][0] = pk_fma_svv(w1rs, invAB, S[j][0]);
      S[j][1] = pk_fma_svv(w1is, invAB, S[j][1]);
      S[j][2] = pk_fma_svv(w2s,  invAB, S[j][2]);
      S[j][3] = pk_fma_svv(w3s,  invAB, S[j][3]);
      S[j][4] = pk_fma_svv(nw1r, vAB, S[j][4]);
      S[j][5] = pk_fma_svv(nw1i, vAB, S[j][5]);
      S[j][6] = pk_fma_svv(nw2,  vAB, S[j][6]);
      S[j][7] = pk_fma_svv(nw3,  vAB, S[j][7]);
    }
  }

  // ---- Phase 1 tail: unpack halves, Woodbury, radix-2 fold, 16B LDS stores.
#pragma unroll
  for (int j = 0; j < 4; ++j) {
    const float2 S1A = make_float2(S[j][0].x, S[j][4].x);
    const float2 S2A = make_float2(S[j][1].x, S[j][5].x);
    const float2 S3A = make_float2(S[j][2].x, S[j][6].x);
    const float2 S4A = make_float2(S[j][3].x, S[j][7].x);
    const float2 S1B = make_float2(S[j][0].y, S[j][4].y);
    const float2 S2B = make_float2(S[j][1].y, S[j][5].y);
    const float2 S3B = make_float2(S[j][2].y, S[j][6].y);
    const float2 S4B = make_float2(S[j][3].y, S[j][7].y);
    const float2 KA = woodbury(S1A, S2A, S3A, S4A, TA[j]);
    const float2 KB = woodbury(S1B, S2B, S3B, S4B, TB[j]);
    ((float4*)xy)[t + (j << 10)] = make_float4(KA.x + KB.x, KA.y + KB.y,
                                               KA.x - KB.x, KA.y - KB.y);
  }
  __syncthreads();

  // ---- Phase 2: six radix-4 DIT stages, spans h = 2,8,32,128,512,2048.
#pragma unroll
  for (int s = 0; s < 6; ++s) {
    const int h = 2 << (2*s);
    const int twsh = 10 - 2*s;                // tw stride = L/(4h) = 1024>>2s
#pragma unroll
    for (int j = 0; j < 2; ++j) {
      const int bb = t + (j << 10);           // butterfly id 0..2047
      const int pos = bb & (h - 1);
      const int i0 = ((bb >> (1 + 2*s)) << (3 + 2*s)) + pos;
      const int ti = pos << twsh;
      const float2 w1 = tw[ti];
      const float2 w2 = tw[2*ti];
      const float2 w3 = tw[3*ti];
      const float2 x0 = xy[i0];
      const float2 x1 = xy[i0 + h];
      const float2 x2 = xy[i0 + 2*h];
      const float2 x3 = xy[i0 + 3*h];
      const float2 t1 = cmul(w1, x1);
      const float2 t2 = cmul(w2, x2);
      const float2 t3 = cmul(w3, x3);
      const float2 u0 = make_float2(x0.x + t2.x, x0.y + t2.y);
      const float2 u1 = make_float2(x0.x - t2.x, x0.y - t2.y);
      const float2 u2 = make_float2(t1.x + t3.x, t1.y + t3.y);
      const float2 vv = make_float2(t1.x - t3.x, t1.y - t3.y);
      xy[i0]         = make_float2(u0.x + u2.x, u0.y + u2.y);   // Y0
      xy[i0 + h]     = make_float2(u1.x - vv.y, u1.y + vv.x);   // Y1 = u1 + i*vv
      xy[i0 + 2*h]   = make_float2(u0.x - u2.x, u0.y - u2.y);   // Y2
      xy[i0 + 3*h]   = make_float2(u1.x + vv.y, u1.y - vv.x);   // Y3 = u1 - i*vv
    }
    __syncthreads();
  }

  // ---- Store real part (already scaled by 1/L), natural order, coalesced.
  float* orow = out + (size_t)d * LSEQ;
#pragma unroll
  for (int j = 0; j < 8; ++j) orow[t + (j << 10)] = xy[t + (j << 10)].x;

  // second tuple output: D passthrough (zeros buffer)
  if (d == 0 && t < DMODEL) out[(size_t)DMODEL * LSEQ + t] = Din[t];
}

// ---------------------------------------------------------------- launch
extern "C" void kernel_launch(void* const* d_in, const int* in_sizes, int n_in,
                              void* d_out, int out_size, void* d_ws, size_t ws_size,
                              hipStream_t stream)
{
  const float* Lre    = (const float*)d_in[0];
  const float* Lim    = (const float*)d_in[1];
  const float* Pre    = (const float*)d_in[2];
  const float* Pim    = (const float*)d_in[3];
  const float* Bre    = (const float*)d_in[4];
  const float* Bim    = (const float*)d_in[5];
  const float* log_dt = (const float*)d_in[6];
  const float* Din    = (const float*)d_in[7];
  float* out = (float*)d_out;
  char* ws = (char*)d_ws;

  hipLaunchKernelGGL(precompute_kernel, dim3(64), dim3(256), 0, stream,
                     Lre, Lim, Pre, Pim, Bre, Bim, log_dt, ws);
  hipLaunchKernelGGL(fused_kernel, dim3(DMODEL), dim3(1024), 0, stream,
                     (const float2*)(ws + OFF_DN), (const float*)(ws + OFF_CDT),
                     (const float2*)(ws + OFF_TW), Din, out);
}

// Round 5
// 126.791 us; speedup vs baseline: 1.2748x; 1.0535x over previous
//
#include <hip/hip_runtime.h>
#include <math.h>

#ifndef M_PI
#define M_PI 3.14159265358979323846
#endif

#define DMODEL 256
#define NSTATE 64
#define LSEQ   8192
#define INVL   (1.0f/8192.0f)

// Workspace layout (bytes). tw 48 KB + dn 1.25 MB + cdt 1 KB.
#define OFF_TW  0                                  // float2[6144]: e^{+2pi i j/L}, j<3L/4
#define OFF_DN  (6144*8)                           // float2[10*DMODEL*NSTATE] duplicated pairs
#define OFF_CDT (OFF_DN + DMODEL*NSTATE*80)        // float[DMODEL]: 2/dt

__device__ __forceinline__ float sin_rev(float r) {
#if __has_builtin(__builtin_amdgcn_sinf)
  return __builtin_amdgcn_sinf(r);        // D = sin(S0 * 2pi), input in revolutions
#else
  return __sinf(r * 6.283185307179586f);
#endif
}
__device__ __forceinline__ float cos_rev(float r) {
#if __has_builtin(__builtin_amdgcn_cosf)
  return __builtin_amdgcn_cosf(r);
#else
  return __cosf(r * 6.283185307179586f);
#endif
}

__device__ __forceinline__ float2 cmul(float2 a, float2 b) {
  return make_float2(a.x*b.x - a.y*b.y, a.x*b.y + a.y*b.x);
}

// Packed fp32 (CDNA full-rate VOP3P, 64-bit register pairs): 2 FLOPs/lane/issue.
// Weight operands live in SGPR pairs (wave-uniform, duplicated lo==hi);
// each instruction reads exactly ONE scalar operand (legal: <=1 SGPR/VALU op).
__device__ __forceinline__ float2 pk_add_sv(float2 s, float2 v) {
  float2 d; asm("v_pk_add_f32 %0, %1, %2" : "=v"(d) : "s"(s), "v"(v)); return d;
}
__device__ __forceinline__ float2 pk_mul_vv(float2 a, float2 b) {
  float2 d; asm("v_pk_mul_f32 %0, %1, %2" : "=v"(d) : "v"(a), "v"(b)); return d;
}
__device__ __forceinline__ float2 pk_fma_vvs(float2 a, float2 b, float2 s) {
  float2 d; asm("v_pk_fma_f32 %0, %1, %2, %3" : "=v"(d) : "v"(a), "v"(b), "s"(s)); return d;
}
__device__ __forceinline__ float2 pk_fma_svv(float2 s, float2 b, float2 c) {
  float2 d; asm("v_pk_fma_f32 %0, %1, %2, %3" : "=v"(d) : "s"(s), "v"(b), "v"(c)); return d;
}

// K_hat/L from the 4 complex sums. PRB*BRP = (S1+iS2)(S1-iS2) = S1^2 + S2^2.
// Prefactor 2/(1+z) = 1 + i*T; fold 1/L here.
__device__ __forceinline__ float2 woodbury(float2 S1, float2 S2, float2 S3,
                                           float2 S4, float T) {
  float nr = (S1.x*S1.x - S1.y*S1.y) + (S2.x*S2.x - S2.y*S2.y);
  float ni = 2.0f*(S1.x*S1.y + S2.x*S2.y);
  float dr = 1.0f + S3.x, di = S3.y;
  float inv = __builtin_amdgcn_rcpf(fmaf(dr, dr, di*di));
  float qr = (nr*dr + ni*di) * inv;
  float qi = (ni*dr - nr*di) * inv;
  float vr = S4.x - qr, vi = S4.y - qi;
  return make_float2((vr - T*vi)*INVL, (vi + T*vr)*INVL);
}

// ---------------------------------------------------------------- precompute
// dn layout per (d,n), 10 float2 of DUPLICATED pairs (for packed VOP3P ops):
//   [0]=(-lim,-lim) [1]=(sp^2,sp^2) [2]=(w1r*sp,..) [3]=(w1i*sp,..) [4]=(w2*sp,..)
//   [5]=(w3*sp,..)  [6]=(-w1r,..)   [7]=(-w1i,..)   [8]=(-w2,..)    [9]=(-w3,..)
// Re-sums use (w*sp)*inv; Im-sums use (-w)*(dim*inv).
__global__ __launch_bounds__(256) void precompute_kernel(
    const float* __restrict__ Lre, const float* __restrict__ Lim,
    const float* __restrict__ Pre, const float* __restrict__ Pim,
    const float* __restrict__ Bre, const float* __restrict__ Bim,
    const float* __restrict__ log_dt, char* __restrict__ ws)
{
  const int t = blockIdx.x * blockDim.x + threadIdx.x;  // 0..16383
  float2* tw  = (float2*)(ws + OFF_TW);
  float2* dn  = (float2*)(ws + OFF_DN);
  float*  cdt = (float*)(ws + OFF_CDT);

  if (t < 6144) {
    double th = (2.0 * M_PI / (double)LSEQ) * (double)t;
    double s, c; sincos(th, &s, &c);
    tw[t] = make_float2((float)c, (float)s);
  }
  {
    float lre = Lre[t], lim = Lim[t];
    float pre = Pre[t], pim = Pim[t];
    float bre = Bre[t], bim = Bim[t];
    float sp = fmaxf(lre, 0.0f) + log1pf(expf(-fabsf(lre)));  // softplus
    float w1r = pre*bre + pim*bim;   // Re conj(P)*B
    float w1i = pre*bim - pim*bre;   // Im conj(P)*B
    float w2  = pre*pre + pim*pim;   // |P|^2
    float w3  = bre*bre + bim*bim;   // |B|^2
    float2* e = dn + 10*(size_t)t;
    e[0] = make_float2(-lim, -lim);
    e[1] = make_float2(sp*sp, sp*sp);
    e[2] = make_float2(w1r*sp, w1r*sp);
    e[3] = make_float2(w1i*sp, w1i*sp);
    e[4] = make_float2(w2*sp, w2*sp);
    e[5] = make_float2(w3*sp, w3*sp);
    e[6] = make_float2(-w1r, -w1r);
    e[7] = make_float2(-w1i, -w1i);
    e[8] = make_float2(-w2, -w2);
    e[9] = make_float2(-w3, -w3);
  }
  if (t < DMODEL) cdt[t] = 2.0f * expf(-log_dt[t]);
}

// ---------------------------------------------------------------- fused cauchy + ifft
// One block per d. hipcc pins 1024-thread blocks at 64 VGPR (observed R2/R4,
// launch_bounds hint ignored) -- so phase 1 is sized to FIT 64 VGPR: two
// passes, each with TWO packed (kA, kA+4096) pairs live (S[2][8]=32 VGPR +
// temps ~= 58 live). A/B halves of each pair occupy lo/hi slots of v_pk_*
// (11 packed VALU + 2 rcp per (n,pair) vs 22+2 unpacked). Weights stream
// through SGPRs (wave-uniform s_load) directly into the VOP3P scalar slot.
// Phase 2: 6 radix-4 DIT stages in LDS. Output natural order.
__global__ __launch_bounds__(1024) void fused_kernel(
    const float2* __restrict__ dn_all, const float* __restrict__ cdt,
    const float2* __restrict__ tw, const float* __restrict__ Din,
    float* __restrict__ out)
{
  __shared__ __align__(16) float2 xy[LSEQ];   // 64 KB
  const int d = blockIdx.x;
  const int t = threadIdx.x;                  // 0..1023
  const float c = cdt[d];                     // 2/dt, wave-uniform
  const float2* dn = dn_all + (size_t)d * (10*NSTATE);

  // ---- Phase 1: two passes, two packed pairs per pass.
  for (int pass = 0; pass < 2; ++pass) {
    float TA[2], TB[2];
    float2 gAB[2];
    float2 S[2][8];   // [pair][S1x,S2x,S3x,S4x,S1y,S2y,S3y,S4y]; x=Re-sum, y=Im-sum; packed (A,B)
#pragma unroll
    for (int j = 0; j < 2; ++j) {
      const int b = t + ((2*pass + j) << 10); // pair id 0..4095
      const unsigned p = (unsigned)(2*b);
      const unsigned r = __brev(p) >> 19;     // 13-bit reversal
      const int kA = (int)((r & 0x1000u) | ((r & 0x0555u) << 1) | ((r & 0x0AAAu) >> 1));
      // kA < 4096. T = tan(pi k / L); (1-z)/(1+z) = i*T exactly (no cancellation).
      const float rev = (float)kA * (1.0f/16384.0f);
      const float sA = sin_rev(rev), cA = cos_rev(rev);
      float ta = sA * __builtin_amdgcn_rcpf(cA);
      float tb = -cA * __builtin_amdgcn_rcpf(sA);   // tan(x + pi/2) = -cot(x)
      ta = fminf(fmaxf(ta, -1e7f), 1e7f);
      tb = fminf(fmaxf(tb, -1e7f), 1e7f);
      TA[j] = ta; TB[j] = tb;
      gAB[j] = make_float2(c * ta, c * tb);   // g = i*gIm, purely imaginary
#pragma unroll
      for (int q = 0; q < 8; ++q) S[j][q] = make_float2(0.0f, 0.0f);
    }

#pragma unroll 2
    for (int n = 0; n < NSTATE; ++n) {
      const float2* e = dn + 10*n;
      const float2 nl2  = e[0];   // (-lim,-lim)      wave-uniform -> SGPR pair
      const float2 s2_2 = e[1];   // (sp^2,sp^2)
      const float2 w1rs = e[2];
      const float2 w1is = e[3];
      const float2 w2s  = e[4];
      const float2 w3s  = e[5];
      const float2 nw1r = e[6];
      const float2 nw1i = e[7];
      const float2 nw2  = e[8];
      const float2 nw3  = e[9];
#pragma unroll
      for (int j = 0; j < 2; ++j) {
        const float2 dimAB = pk_add_sv(nl2, gAB[j]);           // g - lim (both halves)
        const float2 denAB = pk_fma_vvs(dimAB, dimAB, s2_2);   // dim^2 + sp^2
        float2 invAB;
        invAB.x = __builtin_amdgcn_rcpf(denAB.x);
        invAB.y = __builtin_amdgcn_rcpf(denAB.y);
        const float2 vAB = pk_mul_vv(dimAB, invAB);            // Im R = -v; Re R = sp*inv
        S[j][0] = pk_fma_svv(w1rs, invAB, S[j][0]);
        S[j][1] = pk_fma_svv(w1is, invAB, S[j][1]);
        S[j][2] = pk_fma_svv(w2s,  invAB, S[j][2]);
        S[j][3] = pk_fma_svv(w3s,  invAB, S[j][3]);
        S[j][4] = pk_fma_svv(nw1r, vAB, S[j][4]);
        S[j][5] = pk_fma_svv(nw1i, vAB, S[j][5]);
        S[j][6] = pk_fma_svv(nw2,  vAB, S[j][6]);
        S[j][7] = pk_fma_svv(nw3,  vAB, S[j][7]);
      }
    }

    // Tail: unpack halves, Woodbury, radix-2 fold, 16B conflict-free LDS store.
#pragma unroll
    for (int j = 0; j < 2; ++j) {
      const float2 S1A = make_float2(S[j][0].x, S[j][4].x);
      const float2 S2A = make_float2(S[j][1].x, S[j][5].x);
      const float2 S3A = make_float2(S[j][2].x, S[j][6].x);
      const float2 S4A = make_float2(S[j][3].x, S[j][7].x);
      const float2 S1B = make_float2(S[j][0].y, S[j][4].y);
      const float2 S2B = make_float2(S[j][1].y, S[j][5].y);
      const float2 S3B = make_float2(S[j][2].y, S[j][6].y);
      const float2 S4B = make_float2(S[j][3].y, S[j][7].y);
      const float2 KA = woodbury(S1A, S2A, S3A, S4A, TA[j]);
      const float2 KB = woodbury(S1B, S2B, S3B, S4B, TB[j]);
      ((float4*)xy)[t + ((2*pass + j) << 10)] =
          make_float4(KA.x + KB.x, KA.y + KB.y, KA.x - KB.x, KA.y - KB.y);
    }
  }
  __syncthreads();

  // ---- Phase 2: six radix-4 DIT stages, spans h = 2,8,32,128,512,2048.
#pragma unroll
  for (int s = 0; s < 6; ++s) {
    const int h = 2 << (2*s);
    const int twsh = 10 - 2*s;                // tw stride = L/(4h) = 1024>>2s
#pragma unroll
    for (int j = 0; j < 2; ++j) {
      const int bb = t + (j << 10);           // butterfly id 0..2047
      const int pos = bb & (h - 1);
      const int i0 = ((bb >> (1 + 2*s)) << (3 + 2*s)) + pos;
      const int ti = pos << twsh;
      const float2 w1 = tw[ti];
      const float2 w2 = tw[2*ti];
      const float2 w3 = tw[3*ti];
      const float2 x0 = xy[i0];
      const float2 x1 = xy[i0 + h];
      const float2 x2 = xy[i0 + 2*h];
      const float2 x3 = xy[i0 + 3*h];
      const float2 t1 = cmul(w1, x1);
      const float2 t2 = cmul(w2, x2);
      const float2 t3 = cmul(w3, x3);
      const float2 u0 = make_float2(x0.x + t2.x, x0.y + t2.y);
      const float2 u1 = make_float2(x0.x - t2.x, x0.y - t2.y);
      const float2 u2 = make_float2(t1.x + t3.x, t1.y + t3.y);
      const float2 vv = make_float2(t1.x - t3.x, t1.y - t3.y);
      xy[i0]         = make_float2(u0.x + u2.x, u0.y + u2.y);   // Y0
      xy[i0 + h]     = make_float2(u1.x - vv.y, u1.y + vv.x);   // Y1 = u1 + i*vv
      xy[i0 + 2*h]   = make_float2(u0.x - u2.x, u0.y - u2.y);   // Y2
      xy[i0 + 3*h]   = make_float2(u1.x + vv.y, u1.y - vv.x);   // Y3 = u1 - i*vv
    }
    __syncthreads();
  }

  // ---- Store real part (already scaled by 1/L), natural order, coalesced.
  float* orow = out + (size_t)d * LSEQ;
#pragma unroll
  for (int j = 0; j < 8; ++j) orow[t + (j << 10)] = xy[t + (j << 10)].x;

  // second tuple output: D passthrough (zeros buffer)
  if (d == 0 && t < DMODEL) out[(size_t)DMODEL * LSEQ + t] = Din[t];
}

// ---------------------------------------------------------------- launch
extern "C" void kernel_launch(void* const* d_in, const int* in_sizes, int n_in,
                              void* d_out, int out_size, void* d_ws, size_t ws_size,
                              hipStream_t stream)
{
  const float* Lre    = (const float*)d_in[0];
  const float* Lim    = (const float*)d_in[1];
  const float* Pre    = (const float*)d_in[2];
  const float* Pim    = (const float*)d_in[3];
  const float* Bre    = (const float*)d_in[4];
  const float* Bim    = (const float*)d_in[5];
  const float* log_dt = (const float*)d_in[6];
  const float* Din    = (const float*)d_in[7];
  float* out = (float*)d_out;
  char* ws = (char*)d_ws;

  hipLaunchKernelGGL(precompute_kernel, dim3(64), dim3(256), 0, stream,
                     Lre, Lim, Pre, Pim, Bre, Bim, log_dt, ws);
  hipLaunchKernelGGL(fused_kernel, dim3(DMODEL), dim3(1024), 0, stream,
                     (const float2*)(ws + OFF_DN), (const float*)(ws + OFF_CDT),
                     (const float2*)(ws + OFF_TW), Din, out);
}